// Round 9
// baseline (166.269 us; speedup 1.0000x reference)
//
#include <hip/hip_runtime.h>
#include <hip/hip_bf16.h>

#define DIM 768
#define NHEADS 12
#define HD 64
#define NTOK 197
#define BATCH 64
#define NTOKENS (BATCH*NTOK)          // 12608
#define NPAIR (NTOK*NTOK)             // 38809
#define QK_SCALE 0.125f               // 64^-0.5
#define CDIM 2304                     // qkv row width

typedef short bf16x8 __attribute__((ext_vector_type(8)));
typedef float f32x4 __attribute__((ext_vector_type(4)));

#define MFMA(a,b,c) __builtin_amdgcn_mfma_f32_16x16x32_bf16(a,b,c,0,0,0)

__device__ __forceinline__ unsigned short f2bf(float f) {
    union { float f; unsigned u; } v; v.f = f;
    unsigned r = v.u + 0x7FFFu + ((v.u >> 16) & 1u);
    return (unsigned short)(r >> 16);
}

__device__ __forceinline__ void gload16(const unsigned short* g, unsigned short* l) {
    __builtin_amdgcn_global_load_lds(
        (const __attribute__((address_space(1))) void*)g,
        (__attribute__((address_space(3))) void*)l, 16, 0, 0);
}

// bijective XCD-aware block swizzle (m204)
__device__ __forceinline__ int xcd_swz(int orig, int nwg) {
    int q = nwg >> 3, r = nwg & 7;
    int xcd = orig & 7, idx = orig >> 3;
    return (xcd < r ? xcd * (q + 1) : r * (q + 1) + (xcd - r) * q) + idx;
}

// ---------------- fused prep: 3x fp32->bf16 convert + bias gather (f32)
#define NB_X 4728     // NELEM/8/256
#define NB_WQ 864     // WQKV/8/256
#define NB_WP 288     // WPROJ/8/256
#define NB_BIAS 1820  // ceil(465708/256)

__device__ __forceinline__ void cvt8(const float* __restrict__ s,
                                     unsigned short* __restrict__ d, int t, int n8) {
    if (t >= n8) return;
    float4 a = ((const float4*)s)[t * 2], b = ((const float4*)s)[t * 2 + 1];
    union { unsigned short u[8]; bf16x8 v; } p;
    p.u[0] = f2bf(a.x); p.u[1] = f2bf(a.y); p.u[2] = f2bf(a.z); p.u[3] = f2bf(a.w);
    p.u[4] = f2bf(b.x); p.u[5] = f2bf(b.y); p.u[6] = f2bf(b.z); p.u[7] = f2bf(b.w);
    ((bf16x8*)d)[t] = p.v;
}

__global__ __launch_bounds__(256) void prep(
    const float* __restrict__ x, const float* __restrict__ qw,
    const float* __restrict__ pw, const float* __restrict__ rpb,
    const int* __restrict__ rel,
    unsigned short* __restrict__ Xb, unsigned short* __restrict__ Wqb,
    unsigned short* __restrict__ Wpb, float* __restrict__ biasm)
{
    int bid = blockIdx.x;
    if (bid < NB_X) {
        cvt8(x, Xb, bid * 256 + threadIdx.x, NB_X * 256);
    } else if (bid < NB_X + NB_WQ) {
        cvt8(qw, Wqb, (bid - NB_X) * 256 + threadIdx.x, NB_WQ * 256);
    } else if (bid < NB_X + NB_WQ + NB_WP) {
        cvt8(pw, Wpb, (bid - NB_X - NB_WQ) * 256 + threadIdx.x, NB_WP * 256);
    } else {
        int t = (bid - NB_X - NB_WQ - NB_WP) * 256 + threadIdx.x;
        if (t < NHEADS * NPAIR) {
            int h = t / NPAIR, p = t - h * NPAIR;
            biasm[t] = rpb[rel[p] * NHEADS + h];
        }
    }
}

// ---------------- shared 8-phase GEMM machinery (256x256, BK=64, 8 waves)
#define NKT 12
#define TMAX 6         // NKT/2 iterations
#define BUFE 16384

// per-phase: {frag ds_reads | stage one half-tile | barrier | 16 MFMA | [vmcnt] | barrier}
#define LDA(bo, mh) do { _Pragma("unroll") for (int mi = 0; mi < 4; ++mi) { \
    af[mi][0] = *(const bf16x8*)&AsF[(bo) + abase0 + ((mh)*4+mi)*1024 + sl0*8]; \
    af[mi][1] = *(const bf16x8*)&AsF[(bo) + abase0 + ((mh)*4+mi)*1024 + sl1*8]; } } while(0)
#define LDB(bo, nh) do { _Pragma("unroll") for (int ni = 0; ni < 2; ++ni) { \
    bw[ni][0] = *(const bf16x8*)&BsF[(bo) + bbase0 + ((nh)*2+ni)*1024 + sl0*8]; \
    bw[ni][1] = *(const bf16x8*)&BsF[(bo) + bbase0 + ((nh)*2+ni)*1024 + sl1*8]; } } while(0)
#define MM(mh, nh) do { __builtin_amdgcn_s_setprio(1); \
    _Pragma("unroll") for (int mi = 0; mi < 4; ++mi) \
    _Pragma("unroll") for (int ni = 0; ni < 2; ++ni) { \
        acc[(mh)*4+mi][(nh)*2+ni] = MFMA(af[mi][0], bw[ni][0], acc[(mh)*4+mi][(nh)*2+ni]); \
        acc[(mh)*4+mi][(nh)*2+ni] = MFMA(af[mi][1], bw[ni][1], acc[(mh)*4+mi][(nh)*2+ni]); } \
    __builtin_amdgcn_s_setprio(0); } while(0)
#define SA(Ap, buf, h, kt) do { \
    gload16(Ap + asrc[2*(h)] + (kt)*64, &AsF[(buf)*BUFE + adoff[2*(h)]]); \
    gload16(Ap + asrc[2*(h)+1] + (kt)*64, &AsF[(buf)*BUFE + adoff[2*(h)+1]]); } while(0)
#define SB(Bp, buf, h, kt) do { \
    gload16(Bp + bsrc[2*(h)] + (kt)*64, &BsF[(buf)*BUFE + adoff[2*(h)]]); \
    gload16(Bp + bsrc[2*(h)+1] + (kt)*64, &BsF[(buf)*BUFE + adoff[2*(h)+1]]); } while(0)
#define BAR __builtin_amdgcn_s_barrier()
#define WVM0 asm volatile("s_waitcnt vmcnt(0)" ::: "memory")

// 8-phase main loop: iteration t computes K-tiles 2t (buf0) / 2t+1 (buf1);
// phases 1-4 stage tile 2t+1 (landed by ph4's vmcnt, read ph5-8);
// phases 5-8 stage tile 2t+2 into buf0 (landed by ph8's vmcnt, read next ph1-4).
#define KLOOP(Ap, Bp) \
    SA(Ap, 0, 0, 0); SA(Ap, 0, 1, 0); SB(Bp, 0, 0, 0); SB(Bp, 0, 1, 0); \
    WVM0; BAR; \
    for (int t = 0; t < TMAX; ++t) { \
        int k1 = 2 * t + 1, k2 = 2 * t + 2; \
        bool st = (t < TMAX - 1); \
        LDA(0, 0); LDB(0, 0); SA(Ap, 1, 0, k1);            BAR; MM(0, 0); BAR; \
        LDB(0, 1);            SA(Ap, 1, 1, k1);            BAR; MM(0, 1); BAR; \
        LDA(0, 1);            SB(Bp, 1, 0, k1);            BAR; MM(1, 1); BAR; \
        LDB(0, 0);            SB(Bp, 1, 1, k1);            BAR; MM(1, 0); WVM0; BAR; \
        LDA(BUFE, 0); LDB(BUFE, 0); if (st) SA(Ap, 0, 0, k2); BAR; MM(0, 0); BAR; \
        LDB(BUFE, 1);               if (st) SA(Ap, 0, 1, k2); BAR; MM(0, 1); BAR; \
        LDA(BUFE, 1);               if (st) SB(Bp, 0, 0, k2); BAR; MM(1, 1); BAR; \
        LDB(BUFE, 0);               if (st) SB(Bp, 0, 1, k2); BAR; MM(1, 0); \
        if (st) { WVM0; } BAR; \
    }

// ---------------- GEMM1: qkv[token][2304] = Xb @ Wb^T (+bias, Q pre-scaled)
__global__ __launch_bounds__(512, 2) void gemm_qkv8(
    const unsigned short* __restrict__ Xb, const unsigned short* __restrict__ Wb,
    const float* __restrict__ qbias, const float* __restrict__ vbias,
    unsigned short* __restrict__ QKVb)
{
    __shared__ __attribute__((aligned(16))) unsigned short AsF[2 * BUFE];
    __shared__ __attribute__((aligned(16))) unsigned short BsF[2 * BUFE];
    int tid = threadIdx.x, lane = tid & 63, wid = tid >> 6;
    int wr = wid >> 2, wc = wid & 3;
    int wg = xcd_swz(blockIdx.x, 450);
    int bx = wg / 9, by = wg % 9;             // consecutive wg share X-panel
    int m0 = bx * 256, n0 = by * 256;
    int r15 = lane & 15, hi = lane >> 4, sx = lane & 7;
    int sl0 = hi ^ sx, sl1 = (hi + 4) ^ sx;

    size_t asrc[4], bsrc[4];
    int adoff[4];
    #pragma unroll
    for (int i = 0; i < 4; ++i) {
        int c = i * 512 + tid;
        int row = c >> 3, s = c & 7, rr = row & 127, half = row >> 7;
        int slot = s ^ (rr & 7);
        int ar = m0 + row; if (ar >= NTOKENS) ar = NTOKENS - 1;
        asrc[i] = (size_t)ar * DIM + slot * 8;
        bsrc[i] = (size_t)(n0 + row) * DIM + slot * 8;
        adoff[i] = half * 8192 + rr * 64 + s * 8;
    }
    int abase0 = wr * 8192 + r15 * 64;
    int bbase0 = (wc >> 1) * 8192 + (wc & 1) * 4096 + r15 * 64;

    f32x4 acc[8][4];
    #pragma unroll
    for (int i = 0; i < 8; ++i)
        #pragma unroll
        for (int j = 0; j < 4; ++j) acc[i][j] = (f32x4){0.f, 0.f, 0.f, 0.f};

    bf16x8 af[4][2], bw[2][2];
    KLOOP(Xb, Wb)

    // epilogue: bias+scale in regs -> per-wave LDS transpose -> coalesced stores
    unsigned short* reg = (wid < 4) ? &AsF[wid * 8192] : &BsF[(wid - 4) * 8192];
    {
        int which = n0 / DIM;
        float scl = (which == 0) ? QK_SCALE : 1.f;
        #pragma unroll
        for (int n = 0; n < 4; ++n) {
            int colr = n0 - which * DIM + wc * 64 + n * 16 + r15;
            float bv = (which == 0) ? qbias[colr] : (which == 2 ? vbias[colr] : 0.f);
            #pragma unroll
            for (int m = 0; m < 8; ++m) {
                int lrb = m * 16 + hi * 4;
                #pragma unroll
                for (int r = 0; r < 4; ++r) {
                    int lr = lrb + r;
                    int c = n * 16 + r15;
                    reg[lr * 64 + (c ^ (((lr >> 2) & 3) << 4))] =
                        f2bf((acc[m][n][r] + bv) * scl);
                }
            }
        }
    }
    #pragma unroll
    for (int it = 0; it < 16; ++it) {
        int c = it * 64 + lane;
        int lr = c >> 3, cc = c & 7;
        int row = m0 + wr * 128 + lr;
        if (row < NTOKENS) {
            bf16x8 v = *(bf16x8*)&reg[lr * 64 + ((cc * 8) ^ (((lr >> 2) & 3) << 4))];
            *(bf16x8*)(QKVb + (size_t)row * CDIM + n0 + wc * 64 + cc * 8) = v;
        }
    }
}

// ---------------- GEMM2: out = O @ Wp^T + proj_b (fp32), same 8-phase pipeline
__global__ __launch_bounds__(512, 2) void gemm_proj8(
    const unsigned short* __restrict__ Ob, const unsigned short* __restrict__ Wp,
    const float* __restrict__ pbias, float* __restrict__ out)
{
    __shared__ __attribute__((aligned(16))) unsigned short AsF[2 * BUFE];
    __shared__ __attribute__((aligned(16))) unsigned short BsF[2 * BUFE];
    int tid = threadIdx.x, lane = tid & 63, wid = tid >> 6;
    int wr = wid >> 2, wc = wid & 3;
    int wg = xcd_swz(blockIdx.x, 150);
    int bx = wg / 3, by = wg % 3;             // consecutive wg share A-panel
    int m0 = bx * 256, n0 = by * 256;
    int r15 = lane & 15, hi = lane >> 4, sx = lane & 7;
    int sl0 = hi ^ sx, sl1 = (hi + 4) ^ sx;

    size_t asrc[4], bsrc[4];
    int adoff[4];
    #pragma unroll
    for (int i = 0; i < 4; ++i) {
        int c = i * 512 + tid;
        int row = c >> 3, s = c & 7, rr = row & 127, half = row >> 7;
        int slot = s ^ (rr & 7);
        int ar = m0 + row; if (ar >= NTOKENS) ar = NTOKENS - 1;
        asrc[i] = (size_t)ar * DIM + slot * 8;
        bsrc[i] = (size_t)(n0 + row) * DIM + slot * 8;
        adoff[i] = half * 8192 + rr * 64 + s * 8;
    }
    int abase0 = wr * 8192 + r15 * 64;
    int bbase0 = (wc >> 1) * 8192 + (wc & 1) * 4096 + r15 * 64;

    f32x4 acc[8][4];
    #pragma unroll
    for (int i = 0; i < 8; ++i)
        #pragma unroll
        for (int j = 0; j < 4; ++j) acc[i][j] = (f32x4){0.f, 0.f, 0.f, 0.f};

    bf16x8 af[4][2], bw[2][2];
    KLOOP(Ob, Wp)

    // epilogue: fp32 out, 64B-contiguous per 16-lane group
    #pragma unroll
    for (int n = 0; n < 4; ++n) {
        int col = n0 + wc * 64 + n * 16 + r15;
        float bv = pbias[col];
        #pragma unroll
        for (int m = 0; m < 8; ++m) {
            #pragma unroll
            for (int r = 0; r < 4; ++r) {
                int row = m0 + wr * 128 + m * 16 + hi * 4 + r;
                if (row < NTOKENS)
                    out[(size_t)row * DIM + col] = acc[m][n][r] + bv;
            }
        }
    }
}

// ---------------- fused attention: QKV[token][2304] in, O[token][768] out
#define KP 72          // Kl pitch (elems)
#define PP 232         // Pl pitch (elems), 464B rows (16B-aligned)
#define VPITCH 256     // VT pitch (elems) = 32 16B-slots

__global__ __launch_bounds__(256, 2) void attn(
    const unsigned short* __restrict__ QKV, const float* __restrict__ biasm,
    unsigned short* __restrict__ O)
{
    __shared__ __attribute__((aligned(16))) unsigned short VT[64 * VPITCH];   // 32768 B
    __shared__ __attribute__((aligned(16))) unsigned short KlPl[208 * KP];    // 29952 B

    int tid = threadIdx.x, lane = tid & 63, wid = tid >> 6;
    int r15 = lane & 15, hi = lane >> 4;
    int wg = blockIdx.x;
    int g = wg >> 5, qt = (wg >> 3) & 3, p = wg & 7;
    int bh = g * 8 + p;
    int h = bh % NHEADS, b = bh / NHEADS;
    size_t tb = (size_t)b * NTOK;
    int hq = h * 64;
    int rbase = qt * 64 + wid * 16 + hi * 4;

    // (a) K loads first -> K ds_writes drain ONLY K
    int kcol = (tid & 7) * 8;
    bf16x8 kreg[7];
    #pragma unroll
    for (int t = 0; t < 7; ++t) {
        int row = t * 32 + (tid >> 3);
        int rc = row < NTOK ? row : (NTOK - 1);
        kreg[t] = *(const bf16x8*)(QKV + (tb + rc) * CDIM + 768 + hq + kcol);
    }
    #pragma unroll
    for (int t = 0; t < 7; ++t) {
        int row = t * 32 + (tid >> 3);
        if (row < NTOK)
            *(bf16x8*)&KlPl[row * KP + kcol] = kreg[t];
    }

    // (b) V loads into regs (consumed after QK^T)
    bf16x8 v0r[4], v1r[4];
    #pragma unroll
    for (int it = 0; it < 4; ++it) {
        int c = it * 256 + tid;
        int rp = c >> 3, kc = c & 7;
        int r0 = 2 * rp, r1 = 2 * rp + 1;
        bf16x8 z = (bf16x8)(short)0;
        v0r[it] = z; v1r[it] = z;
        if (r0 < NTOK) v0r[it] = *(const bf16x8*)(QKV + (tb + r0) * CDIM + 1536 + hq + kc * 8);
        if (r1 < NTOK) v1r[it] = *(const bf16x8*)(QKV + (tb + r1) * CDIM + 1536 + hq + kc * 8);
    }

    // (c) Q fragments
    int qrow_g = qt * 64 + wid * 16 + r15;
    int qsrc = qrow_g < NTOK ? qrow_g : (NTOK - 1);
    bf16x8 aq[2];
    #pragma unroll
    for (int ks = 0; ks < 2; ++ks)
        aq[ks] = *(const bf16x8*)(QKV + (tb + qsrc) * CDIM + hq + ks * 32 + hi * 8);

    // (d) bias prefetch (f32; latency hides under QK^T)
    float breg[4][13];
    {
        const float* bb = biasm + h * NPAIR;
        #pragma unroll
        for (int r = 0; r < 4; ++r) {
            int row_g = rbase + r;
            int rowc = row_g < NTOK ? row_g : (NTOK - 1);
            const float* brow = bb + rowc * NTOK + r15;
            #pragma unroll
            for (int t = 0; t < 13; ++t) {
                int off = t * 16;
                if (t == 12 && r15 >= 5) off = 0;
                breg[r][t] = brow[off];
            }
        }
    }
    __syncthreads();

    // S = Q K^T
    f32x4 sa[13];
    #pragma unroll
    for (int t = 0; t < 13; ++t) sa[t] = (f32x4){0.f,0.f,0.f,0.f};
    __builtin_amdgcn_s_setprio(1);
    #pragma unroll
    for (int t = 0; t < 13; ++t) {
        #pragma unroll
        for (int ks = 0; ks < 2; ++ks) {
            bf16x8 bk = *(bf16x8*)&KlPl[(t * 16 + r15) * KP + ks * 32 + hi * 8];
            sa[t] = MFMA(aq[ks], bk, sa[t]);
        }
    }
    __builtin_amdgcn_s_setprio(0);
    __syncthreads();          // all waves past QK^T: Kl region becomes Pl

    // V regs -> VT (swizzled)
    #pragma unroll
    for (int it = 0; it < 4; ++it) {
        int c = it * 256 + tid;
        int rp = c >> 3, kc = c & 7;
        if (rp < 112) {
            #pragma unroll
            for (int j = 0; j < 8; ++j) {
                unsigned int w = (unsigned int)(unsigned short)v0r[it][j] |
                                 ((unsigned int)(unsigned short)v1r[it][j] << 16);
                int slot2 = (rp >> 2) ^ j ^ kc;
                *(unsigned int*)&VT[(kc * 8 + j) * VPITCH + slot2 * 8 + (rp & 3) * 2] = w;
            }
        }
    }

    // softmax (unnormalized; 1/sum deferred) -> P into KlPl region
    int plbase = wid * (16 * PP);
    float invr[4];
    #pragma unroll
    for (int r = 0; r < 4; ++r) {
        #pragma unroll
        for (int t = 0; t < 13; ++t) {
            int col = t * 16 + r15;
            if (col < NTOK) sa[t][r] += breg[r][t];
            else            sa[t][r] = -1e30f;
        }
        float mx = sa[0][r];
        #pragma unroll
        for (int t = 1; t < 13; ++t) mx = fmaxf(mx, sa[t][r]);
        #pragma unroll
        for (int m = 1; m < 16; m <<= 1) mx = fmaxf(mx, __shfl_xor(mx, m));
        float sum = 0.f;
        #pragma unroll
        for (int t = 0; t < 13; ++t) {
            float e = __expf(sa[t][r] - mx);
            sa[t][r] = e; sum += e;
        }
        int roff = plbase + (hi * 4 + r) * PP;
        #pragma unroll
        for (int t = 0; t < 13; ++t)
            KlPl[roff + t * 16 + r15] = f2bf(sa[t][r]);
        KlPl[roff + 208 + r15] = 0;
        #pragma unroll
        for (int m = 1; m < 16; m <<= 1) sum += __shfl_xor(sum, m);
        invr[r] = __builtin_amdgcn_rcpf(sum);
    }
    __syncthreads();          // VT fully written

    // O = P V
    f32x4 oa[4];
    #pragma unroll
    for (int dt = 0; dt < 4; ++dt) oa[dt] = (f32x4){0.f,0.f,0.f,0.f};
    int X = hi ^ (r15 & 7) ^ (r15 >> 3);
    __builtin_amdgcn_s_setprio(1);
    #pragma unroll
    for (int ks = 0; ks < 7; ++ks) {
        bf16x8 ap = *(bf16x8*)&KlPl[plbase + r15 * PP + ks * 32 + hi * 8];
        #pragma unroll
        for (int dt = 0; dt < 4; ++dt) {
            int d = dt * 16 + r15;
            int slotp = (ks * 4) ^ (dt * 2) ^ X;
            bf16x8 bv = *(bf16x8*)&VT[d * VPITCH + slotp * 8];
            oa[dt] = MFMA(ap, bv, oa[dt]);
        }
    }
    __builtin_amdgcn_s_setprio(0);

    // O write: scale by 1/sum, per-wave LDS transpose -> 16B stores
    #pragma unroll
    for (int dt = 0; dt < 4; ++dt)
        #pragma unroll
        for (int r = 0; r < 4; ++r)
            KlPl[plbase + (hi * 4 + r) * 72 + dt * 16 + r15] = f2bf(oa[dt][r] * invr[r]);
    #pragma unroll
    for (int it = 0; it < 2; ++it) {
        int c = it * 64 + lane;
        int lr = c >> 3, cc = c & 7;
        int qrow = qt * 64 + wid * 16 + lr;
        if (qrow < NTOK)
            *(bf16x8*)(O + (tb + qrow) * DIM + hq + cc * 8) =
                *(bf16x8*)&KlPl[plbase + lr * 72 + cc * 8];
    }
}

extern "C" void kernel_launch(void* const* d_in, const int* in_sizes, int n_in,
                              void* d_out, int out_size, void* d_ws, size_t ws_size,
                              hipStream_t stream) {
    const float* x      = (const float*)d_in[0];
    const float* qkv_w  = (const float*)d_in[1];
    const float* q_bias = (const float*)d_in[2];
    const float* v_bias = (const float*)d_in[3];
    const float* rpb    = (const float*)d_in[4];
    const float* proj_w = (const float*)d_in[5];
    const float* proj_b = (const float*)d_in[6];
    const int*   rel    = (const int*)d_in[7];
    float* out = (float*)d_out;

    const size_t NELEM = (size_t)NTOKENS * DIM;      // 9,682,944
    const size_t WQKV  = (size_t)3 * DIM * DIM;
    const size_t WPROJ = (size_t)DIM * DIM;
    unsigned short* Xb   = (unsigned short*)d_ws;    // reused as Ob after gemm_qkv8
    unsigned short* Wqb  = Xb + NELEM;
    unsigned short* Wpb  = Wqb + WQKV;
    unsigned short* QKVb = Wpb + WPROJ;              // [12608][2304]
    float* biasm = (float*)(QKVb + (size_t)NTOKENS * CDIM);  // f32 [12][197][197]
    unsigned short* Ob = Xb;

    prep<<<NB_X + NB_WQ + NB_WP + NB_BIAS, 256, 0, stream>>>(
        x, qkv_w, proj_w, rpb, rel, Xb, Wqb, Wpb, biasm);

    gemm_qkv8<<<450, 512, 0, stream>>>(Xb, Wqb, q_bias, v_bias, QKVb);

    attn<<<3072, 256, 0, stream>>>(QKVb, biasm, Ob);

    gemm_proj8<<<150, 512, 0, stream>>>(Ob, Wpb, proj_b, out);
}

// Round 10
// 151.386 us; speedup vs baseline: 1.0983x; 1.0983x over previous
//
#include <hip/hip_runtime.h>
#include <hip/hip_bf16.h>

#define DIM 768
#define NHEADS 12
#define HD 64
#define NTOK 197
#define BATCH 64
#define NTOKENS (BATCH*NTOK)          // 12608
#define NPAIR (NTOK*NTOK)             // 38809
#define QK_SCALE 0.125f               // 64^-0.5
#define CDIM 2304                     // qkv row width

typedef short bf16x8 __attribute__((ext_vector_type(8)));
typedef float f32x4 __attribute__((ext_vector_type(4)));

#define MFMA(a,b,c) __builtin_amdgcn_mfma_f32_16x16x32_bf16(a,b,c,0,0,0)

__device__ __forceinline__ unsigned short f2bf(float f) {
    union { float f; unsigned u; } v; v.f = f;
    unsigned r = v.u + 0x7FFFu + ((v.u >> 16) & 1u);
    return (unsigned short)(r >> 16);
}

__device__ __forceinline__ float bf2f(unsigned short u) {
    union { unsigned v; float f; } x; x.v = ((unsigned)u) << 16; return x.f;
}

__device__ __forceinline__ void gload16(const unsigned short* g, unsigned short* l) {
    __builtin_amdgcn_global_load_lds(
        (const __attribute__((address_space(1))) void*)g,
        (__attribute__((address_space(3))) void*)l, 16, 0, 0);
}

// bijective XCD-aware block swizzle (m204)
__device__ __forceinline__ int xcd_swz(int orig, int nwg) {
    int q = nwg >> 3, r = nwg & 7;
    int xcd = orig & 7, idx = orig >> 3;
    return (xcd < r ? xcd * (q + 1) : r * (q + 1) + (xcd - r) * q) + idx;
}

// ---------------- fused prep: 3x fp32->bf16 convert + bias gather (bf16)
#define NB_X 4728     // NELEM/8/256
#define NB_WQ 864     // WQKV/8/256
#define NB_WP 288     // WPROJ/8/256
#define NB_BIAS 1820  // ceil(465708/256)

__device__ __forceinline__ void cvt8(const float* __restrict__ s,
                                     unsigned short* __restrict__ d, int t, int n8) {
    if (t >= n8) return;
    float4 a = ((const float4*)s)[t * 2], b = ((const float4*)s)[t * 2 + 1];
    union { unsigned short u[8]; bf16x8 v; } p;
    p.u[0] = f2bf(a.x); p.u[1] = f2bf(a.y); p.u[2] = f2bf(a.z); p.u[3] = f2bf(a.w);
    p.u[4] = f2bf(b.x); p.u[5] = f2bf(b.y); p.u[6] = f2bf(b.z); p.u[7] = f2bf(b.w);
    ((bf16x8*)d)[t] = p.v;
}

__global__ __launch_bounds__(256) void prep(
    const float* __restrict__ x, const float* __restrict__ qw,
    const float* __restrict__ pw, const float* __restrict__ rpb,
    const int* __restrict__ rel,
    unsigned short* __restrict__ Xb, unsigned short* __restrict__ Wqb,
    unsigned short* __restrict__ Wpb, unsigned short* __restrict__ biasm)
{
    int bid = blockIdx.x;
    if (bid < NB_X) {
        cvt8(x, Xb, bid * 256 + threadIdx.x, NB_X * 256);
    } else if (bid < NB_X + NB_WQ) {
        cvt8(qw, Wqb, (bid - NB_X) * 256 + threadIdx.x, NB_WQ * 256);
    } else if (bid < NB_X + NB_WQ + NB_WP) {
        cvt8(pw, Wpb, (bid - NB_X - NB_WQ) * 256 + threadIdx.x, NB_WP * 256);
    } else {
        int t = (bid - NB_X - NB_WQ - NB_WP) * 256 + threadIdx.x;
        if (t < NHEADS * NPAIR) {
            int h = t / NPAIR, p = t - h * NPAIR;
            biasm[t] = f2bf(rpb[rel[p] * NHEADS + h]);
        }
    }
}

// ---------------- shared 8-phase GEMM machinery (256x256, BK=64, 8 waves)
#define NKT 12
#define TMAX 6         // NKT/2 iterations
#define BUFE 16384

#define LDA(bo, mh) do { _Pragma("unroll") for (int mi = 0; mi < 4; ++mi) { \
    af[mi][0] = *(const bf16x8*)&AsF[(bo) + abase0 + ((mh)*4+mi)*1024 + sl0*8]; \
    af[mi][1] = *(const bf16x8*)&AsF[(bo) + abase0 + ((mh)*4+mi)*1024 + sl1*8]; } } while(0)
#define LDB(bo, nh) do { _Pragma("unroll") for (int ni = 0; ni < 2; ++ni) { \
    bw[ni][0] = *(const bf16x8*)&BsF[(bo) + bbase0 + ((nh)*2+ni)*1024 + sl0*8]; \
    bw[ni][1] = *(const bf16x8*)&BsF[(bo) + bbase0 + ((nh)*2+ni)*1024 + sl1*8]; } } while(0)
#define MM(mh, nh) do { __builtin_amdgcn_s_setprio(1); \
    _Pragma("unroll") for (int mi = 0; mi < 4; ++mi) \
    _Pragma("unroll") for (int ni = 0; ni < 2; ++ni) { \
        acc[(mh)*4+mi][(nh)*2+ni] = MFMA(af[mi][0], bw[ni][0], acc[(mh)*4+mi][(nh)*2+ni]); \
        acc[(mh)*4+mi][(nh)*2+ni] = MFMA(af[mi][1], bw[ni][1], acc[(mh)*4+mi][(nh)*2+ni]); } \
    __builtin_amdgcn_s_setprio(0); } while(0)
#define SA(Ap, buf, h, kt) do { \
    gload16(Ap + asrc[2*(h)] + (kt)*64, &AsF[(buf)*BUFE + adoff[2*(h)]]); \
    gload16(Ap + asrc[2*(h)+1] + (kt)*64, &AsF[(buf)*BUFE + adoff[2*(h)+1]]); } while(0)
#define SB(Bp, buf, h, kt) do { \
    gload16(Bp + bsrc[2*(h)] + (kt)*64, &BsF[(buf)*BUFE + adoff[2*(h)]]); \
    gload16(Bp + bsrc[2*(h)+1] + (kt)*64, &BsF[(buf)*BUFE + adoff[2*(h)+1]]); } while(0)
#define BAR __builtin_amdgcn_s_barrier()
#define WVM0 asm volatile("s_waitcnt vmcnt(0)" ::: "memory")

#define KLOOP(Ap, Bp) \
    SA(Ap, 0, 0, 0); SA(Ap, 0, 1, 0); SB(Bp, 0, 0, 0); SB(Bp, 0, 1, 0); \
    WVM0; BAR; \
    for (int t = 0; t < TMAX; ++t) { \
        int k1 = 2 * t + 1, k2 = 2 * t + 2; \
        bool st = (t < TMAX - 1); \
        LDA(0, 0); LDB(0, 0); SA(Ap, 1, 0, k1);            BAR; MM(0, 0); BAR; \
        LDB(0, 1);            SA(Ap, 1, 1, k1);            BAR; MM(0, 1); BAR; \
        LDA(0, 1);            SB(Bp, 1, 0, k1);            BAR; MM(1, 1); BAR; \
        LDB(0, 0);            SB(Bp, 1, 1, k1);            BAR; MM(1, 0); WVM0; BAR; \
        LDA(BUFE, 0); LDB(BUFE, 0); if (st) SA(Ap, 0, 0, k2); BAR; MM(0, 0); BAR; \
        LDB(BUFE, 1);               if (st) SA(Ap, 0, 1, k2); BAR; MM(0, 1); BAR; \
        LDA(BUFE, 1);               if (st) SB(Bp, 0, 0, k2); BAR; MM(1, 1); BAR; \
        LDB(BUFE, 0);               if (st) SB(Bp, 0, 1, k2); BAR; MM(1, 0); \
        if (st) { WVM0; } BAR; \
    }

// ---------------- GEMM1: qkv[token][2304] = Xb @ Wb^T (+bias, Q pre-scaled)
__global__ __launch_bounds__(512, 2) void gemm_qkv8(
    const unsigned short* __restrict__ Xb, const unsigned short* __restrict__ Wb,
    const float* __restrict__ qbias, const float* __restrict__ vbias,
    unsigned short* __restrict__ QKVb)
{
    __shared__ __attribute__((aligned(16))) unsigned short AsF[2 * BUFE];
    __shared__ __attribute__((aligned(16))) unsigned short BsF[2 * BUFE];
    int tid = threadIdx.x, lane = tid & 63, wid = tid >> 6;
    int wr = wid >> 2, wc = wid & 3;
    int wg = xcd_swz(blockIdx.x, 450);
    int bx = wg / 9, by = wg % 9;             // consecutive wg share X-panel
    int m0 = bx * 256, n0 = by * 256;
    int r15 = lane & 15, hi = lane >> 4, sx = lane & 7;
    int sl0 = hi ^ sx, sl1 = (hi + 4) ^ sx;

    size_t asrc[4], bsrc[4];
    int adoff[4];
    #pragma unroll
    for (int i = 0; i < 4; ++i) {
        int c = i * 512 + tid;
        int row = c >> 3, s = c & 7, rr = row & 127, half = row >> 7;
        int slot = s ^ (rr & 7);
        int ar = m0 + row; if (ar >= NTOKENS) ar = NTOKENS - 1;
        asrc[i] = (size_t)ar * DIM + slot * 8;
        bsrc[i] = (size_t)(n0 + row) * DIM + slot * 8;
        adoff[i] = half * 8192 + rr * 64 + s * 8;
    }
    int abase0 = wr * 8192 + r15 * 64;
    int bbase0 = (wc >> 1) * 8192 + (wc & 1) * 4096 + r15 * 64;

    f32x4 acc[8][4];
    #pragma unroll
    for (int i = 0; i < 8; ++i)
        #pragma unroll
        for (int j = 0; j < 4; ++j) acc[i][j] = (f32x4){0.f, 0.f, 0.f, 0.f};

    bf16x8 af[4][2], bw[2][2];
    KLOOP(Xb, Wb)

    // epilogue: bias+scale in regs -> per-wave LDS transpose -> coalesced stores
    unsigned short* reg = (wid < 4) ? &AsF[wid * 8192] : &BsF[(wid - 4) * 8192];
    {
        int which = n0 / DIM;
        float scl = (which == 0) ? QK_SCALE : 1.f;
        #pragma unroll
        for (int n = 0; n < 4; ++n) {
            int colr = n0 - which * DIM + wc * 64 + n * 16 + r15;
            float bv = (which == 0) ? qbias[colr] : (which == 2 ? vbias[colr] : 0.f);
            #pragma unroll
            for (int m = 0; m < 8; ++m) {
                int lrb = m * 16 + hi * 4;
                #pragma unroll
                for (int r = 0; r < 4; ++r) {
                    int lr = lrb + r;
                    int c = n * 16 + r15;
                    reg[lr * 64 + (c ^ (((lr >> 2) & 3) << 4))] =
                        f2bf((acc[m][n][r] + bv) * scl);
                }
            }
        }
    }
    #pragma unroll
    for (int it = 0; it < 16; ++it) {
        int c = it * 64 + lane;
        int lr = c >> 3, cc = c & 7;
        int row = m0 + wr * 128 + lr;
        if (row < NTOKENS) {
            bf16x8 v = *(bf16x8*)&reg[lr * 64 + ((cc * 8) ^ (((lr >> 2) & 3) << 4))];
            *(bf16x8*)(QKVb + (size_t)row * CDIM + n0 + wc * 64 + cc * 8) = v;
        }
    }
}

// ---------------- GEMM2: out = O @ Wp^T + proj_b (fp32 out)
// 128x128 tile, 4 waves, 64 KB LDS -> 2 blocks/CU, 594 blocks (full CU fill)
__global__ __launch_bounds__(256, 2) void gemm_proj(
    const unsigned short* __restrict__ Ob, const unsigned short* __restrict__ Wp,
    const float* __restrict__ pbias, float* __restrict__ out)
{
    __shared__ __attribute__((aligned(16))) unsigned short As[128 * 64];
    __shared__ __attribute__((aligned(16))) unsigned short Bs[128 * 64];
    int tid = threadIdx.x, lane = tid & 63, wid = tid >> 6;
    int wg = xcd_swz(blockIdx.x, 594);
    int bx = wg / 6, by = wg % 6;             // consecutive wg share A-panel
    int m0 = bx * 128, n0 = by * 128;
    int wm = (wid >> 1) * 64, wn = (wid & 1) * 64;

    size_t abase[4], bbase[4];
    unsigned short *alds[4], *blds[4];
    #pragma unroll
    for (int i = 0; i < 4; ++i) {
        int chunk = i * 4 + wid;
        int row = chunk * 8 + (lane >> 3);
        int slot = (lane & 7) ^ (row & 7);
        int ar = m0 + row; if (ar >= NTOKENS) ar = NTOKENS - 1;
        abase[i] = (size_t)ar * DIM + slot * 8;
        bbase[i] = (size_t)(n0 + row) * DIM + slot * 8;
        alds[i] = &As[chunk * 512];
        blds[i] = &Bs[chunk * 512];
    }
    int r15 = lane & 15, hi = lane >> 4, sx = lane & 7;
    int s0 = (hi ^ sx) * 8, s1 = ((hi + 4) ^ sx) * 8;
    int arow[4], brow[4];
    #pragma unroll
    for (int i = 0; i < 4; ++i) {
        arow[i] = (wm + i * 16 + r15) * 64;
        brow[i] = (wn + i * 16 + r15) * 64;
    }

    f32x4 acc[4][4];
    #pragma unroll
    for (int i = 0; i < 4; ++i)
        #pragma unroll
        for (int j = 0; j < 4; ++j) acc[i][j] = (f32x4){0.f, 0.f, 0.f, 0.f};

    for (int k0 = 0; k0 < DIM; k0 += 64) {
        __syncthreads();
        #pragma unroll
        for (int i = 0; i < 4; ++i) {
            gload16(Ob + abase[i] + k0, alds[i]);
            gload16(Wp + bbase[i] + k0, blds[i]);
        }
        __syncthreads();
        #pragma unroll
        for (int ks = 0; ks < 2; ++ks) {
            int so = ks ? s1 : s0;
            bf16x8 af[4], bwv[4];
            #pragma unroll
            for (int i = 0; i < 4; ++i) af[i] = *(bf16x8*)&As[arow[i] + so];
            #pragma unroll
            for (int j = 0; j < 4; ++j) bwv[j] = *(bf16x8*)&Bs[brow[j] + so];
            __builtin_amdgcn_s_setprio(1);
            #pragma unroll
            for (int i = 0; i < 4; ++i)
                #pragma unroll
                for (int j = 0; j < 4; ++j)
                    acc[i][j] = MFMA(af[i], bwv[j], acc[i][j]);
            __builtin_amdgcn_s_setprio(0);
        }
    }

    #pragma unroll
    for (int j = 0; j < 4; ++j) {
        int col = n0 + wn + j * 16 + r15;
        float bv = pbias[col];
        #pragma unroll
        for (int i = 0; i < 4; ++i) {
            #pragma unroll
            for (int r = 0; r < 4; ++r) {
                int row = m0 + wm + i * 16 + hi * 4 + r;
                if (row < NTOKENS)
                    out[(size_t)row * DIM + col] = acc[i][j][r] + bv;
            }
        }
    }
}

// ---------------- fused attention: QKV[token][2304] in, O[token][768] out
#define KP 72          // Kl pitch (elems)
#define PP 232         // Pl pitch (elems), 464B rows (16B-aligned)
#define VPITCH 256     // VT pitch (elems) = 32 16B-slots

__global__ __launch_bounds__(256, 2) void attn(
    const unsigned short* __restrict__ QKV, const unsigned short* __restrict__ biasm,
    unsigned short* __restrict__ O)
{
    __shared__ __attribute__((aligned(16))) unsigned short VT[64 * VPITCH];   // 32768 B
    __shared__ __attribute__((aligned(16))) unsigned short KlPl[208 * KP];    // 29952 B

    int tid = threadIdx.x, lane = tid & 63, wid = tid >> 6;
    int r15 = lane & 15, hi = lane >> 4;
    int wg = blockIdx.x;
    int g = wg >> 5, qt = (wg >> 3) & 3, p = wg & 7;
    int bh = g * 8 + p;
    int h = bh % NHEADS, b = bh / NHEADS;
    size_t tb = (size_t)b * NTOK;
    int hq = h * 64;
    int rbase = qt * 64 + wid * 16 + hi * 4;

    // (a) K loads first -> K ds_writes drain ONLY K
    int kcol = (tid & 7) * 8;
    bf16x8 kreg[7];
    #pragma unroll
    for (int t = 0; t < 7; ++t) {
        int row = t * 32 + (tid >> 3);
        int rc = row < NTOK ? row : (NTOK - 1);
        kreg[t] = *(const bf16x8*)(QKV + (tb + rc) * CDIM + 768 + hq + kcol);
    }
    #pragma unroll
    for (int t = 0; t < 7; ++t) {
        int row = t * 32 + (tid >> 3);
        if (row < NTOK)
            *(bf16x8*)&KlPl[row * KP + kcol] = kreg[t];
    }

    // (b) V loads into regs (consumed after QK^T)
    bf16x8 v0r[4], v1r[4];
    #pragma unroll
    for (int it = 0; it < 4; ++it) {
        int c = it * 256 + tid;
        int rp = c >> 3, kc = c & 7;
        int r0 = 2 * rp, r1 = 2 * rp + 1;
        bf16x8 z = (bf16x8)(short)0;
        v0r[it] = z; v1r[it] = z;
        if (r0 < NTOK) v0r[it] = *(const bf16x8*)(QKV + (tb + r0) * CDIM + 1536 + hq + kc * 8);
        if (r1 < NTOK) v1r[it] = *(const bf16x8*)(QKV + (tb + r1) * CDIM + 1536 + hq + kc * 8);
    }

    // (c) Q fragments
    int qrow_g = qt * 64 + wid * 16 + r15;
    int qsrc = qrow_g < NTOK ? qrow_g : (NTOK - 1);
    bf16x8 aq[2];
    #pragma unroll
    for (int ks = 0; ks < 2; ++ks)
        aq[ks] = *(const bf16x8*)(QKV + (tb + qsrc) * CDIM + hq + ks * 32 + hi * 8);

    // (d) bias prefetch (bf16; latency hides under QK^T)
    unsigned short breg[4][13];
    {
        const unsigned short* bb = biasm + h * NPAIR;
        #pragma unroll
        for (int r = 0; r < 4; ++r) {
            int row_g = rbase + r;
            int rowc = row_g < NTOK ? row_g : (NTOK - 1);
            const unsigned short* brow = bb + rowc * NTOK + r15;
            #pragma unroll
            for (int t = 0; t < 13; ++t) {
                int off = t * 16;
                if (t == 12 && r15 >= 5) off = 0;
                breg[r][t] = brow[off];
            }
        }
    }
    __syncthreads();

    // S = Q K^T
    f32x4 sa[13];
    #pragma unroll
    for (int t = 0; t < 13; ++t) sa[t] = (f32x4){0.f,0.f,0.f,0.f};
    __builtin_amdgcn_s_setprio(1);
    #pragma unroll
    for (int t = 0; t < 13; ++t) {
        #pragma unroll
        for (int ks = 0; ks < 2; ++ks) {
            bf16x8 bk = *(bf16x8*)&KlPl[(t * 16 + r15) * KP + ks * 32 + hi * 8];
            sa[t] = MFMA(aq[ks], bk, sa[t]);
        }
    }
    __builtin_amdgcn_s_setprio(0);
    __syncthreads();          // all waves past QK^T: Kl region becomes Pl

    // V regs -> VT (swizzled)
    #pragma unroll
    for (int it = 0; it < 4; ++it) {
        int c = it * 256 + tid;
        int rp = c >> 3, kc = c & 7;
        if (rp < 112) {
            #pragma unroll
            for (int j = 0; j < 8; ++j) {
                unsigned int w = (unsigned int)(unsigned short)v0r[it][j] |
                                 ((unsigned int)(unsigned short)v1r[it][j] << 16);
                int slot2 = (rp >> 2) ^ j ^ kc;
                *(unsigned int*)&VT[(kc * 8 + j) * VPITCH + slot2 * 8 + (rp & 3) * 2] = w;
            }
        }
    }

    // softmax (unnormalized; 1/sum deferred) -> P into KlPl region
    int plbase = wid * (16 * PP);
    float invr[4];
    #pragma unroll
    for (int r = 0; r < 4; ++r) {
        #pragma unroll
        for (int t = 0; t < 13; ++t) {
            int col = t * 16 + r15;
            if (col < NTOK) sa[t][r] += bf2f(breg[r][t]);
            else            sa[t][r] = -1e30f;
        }
        float mx = sa[0][r];
        #pragma unroll
        for (int t = 1; t < 13; ++t) mx = fmaxf(mx, sa[t][r]);
        #pragma unroll
        for (int m = 1; m < 16; m <<= 1) mx = fmaxf(mx, __shfl_xor(mx, m));
        float sum = 0.f;
        #pragma unroll
        for (int t = 0; t < 13; ++t) {
            float e = __expf(sa[t][r] - mx);
            sa[t][r] = e; sum += e;
        }
        int roff = plbase + (hi * 4 + r) * PP;
        #pragma unroll
        for (int t = 0; t < 13; ++t)
            KlPl[roff + t * 16 + r15] = f2bf(sa[t][r]);
        KlPl[roff + 208 + r15] = 0;
        #pragma unroll
        for (int m = 1; m < 16; m <<= 1) sum += __shfl_xor(sum, m);
        invr[r] = __builtin_amdgcn_rcpf(sum);
    }
    __syncthreads();          // VT fully written

    // O = P V
    f32x4 oa[4];
    #pragma unroll
    for (int dt = 0; dt < 4; ++dt) oa[dt] = (f32x4){0.f,0.f,0.f,0.f};
    int X = hi ^ (r15 & 7) ^ (r15 >> 3);
    __builtin_amdgcn_s_setprio(1);
    #pragma unroll
    for (int ks = 0; ks < 7; ++ks) {
        bf16x8 ap = *(bf16x8*)&KlPl[plbase + r15 * PP + ks * 32 + hi * 8];
        #pragma unroll
        for (int dt = 0; dt < 4; ++dt) {
            int d = dt * 16 + r15;
            int slotp = (ks * 4) ^ (dt * 2) ^ X;
            bf16x8 bv = *(bf16x8*)&VT[d * VPITCH + slotp * 8];
            oa[dt] = MFMA(ap, bv, oa[dt]);
        }
    }
    __builtin_amdgcn_s_setprio(0);

    // O write: scale by 1/sum, per-wave LDS transpose -> 16B stores
    #pragma unroll
    for (int dt = 0; dt < 4; ++dt)
        #pragma unroll
        for (int r = 0; r < 4; ++r)
            KlPl[plbase + (hi * 4 + r) * 72 + dt * 16 + r15] = f2bf(oa[dt][r] * invr[r]);
    #pragma unroll
    for (int it = 0; it < 2; ++it) {
        int c = it * 64 + lane;
        int lr = c >> 3, cc = c & 7;
        int qrow = qt * 64 + wid * 16 + lr;
        if (qrow < NTOK)
            *(bf16x8*)(O + (tb + qrow) * DIM + hq + cc * 8) =
                *(bf16x8*)&KlPl[plbase + lr * 72 + cc * 8];
    }
}

extern "C" void kernel_launch(void* const* d_in, const int* in_sizes, int n_in,
                              void* d_out, int out_size, void* d_ws, size_t ws_size,
                              hipStream_t stream) {
    const float* x      = (const float*)d_in[0];
    const float* qkv_w  = (const float*)d_in[1];
    const float* q_bias = (const float*)d_in[2];
    const float* v_bias = (const float*)d_in[3];
    const float* rpb    = (const float*)d_in[4];
    const float* proj_w = (const float*)d_in[5];
    const float* proj_b = (const float*)d_in[6];
    const int*   rel    = (const int*)d_in[7];
    float* out = (float*)d_out;

    const size_t NELEM = (size_t)NTOKENS * DIM;      // 9,682,944
    const size_t WQKV  = (size_t)3 * DIM * DIM;
    const size_t WPROJ = (size_t)DIM * DIM;
    unsigned short* Xb   = (unsigned short*)d_ws;    // reused as Ob after gemm_qkv8
    unsigned short* Wqb  = Xb + NELEM;
    unsigned short* Wpb  = Wqb + WQKV;
    unsigned short* QKVb = Wpb + WPROJ;              // [12608][2304]
    unsigned short* biasm = QKVb + (size_t)NTOKENS * CDIM;   // bf16 [12][197][197]
    unsigned short* Ob = Xb;

    prep<<<NB_X + NB_WQ + NB_WP + NB_BIAS, 256, 0, stream>>>(
        x, qkv_w, proj_w, rpb, rel, Xb, Wqb, Wpb, biasm);

    gemm_qkv8<<<450, 512, 0, stream>>>(Xb, Wqb, q_bias, v_bias, QKVb);

    attn<<<3072, 256, 0, stream>>>(QKVb, biasm, Ob);

    gemm_proj<<<594, 256, 0, stream>>>(Ob, Wpb, proj_b, out);
}